// Round 14
// baseline (11443.352 us; speedup 1.0000x reference)
//
#include <hip/hip_runtime.h>
#include <math.h>

// Problem constants (fixed by setup_inputs)
constexpr int U      = 128;   // UNITS
constexpr int G4     = 512;   // 4*U gate width
constexpr int NCls   = 10;    // classes
constexpr int TSTEPS = 1000;
constexpr int BATCH  = 256;

// ---------------------------------------------------------------------------
// Evidence ledger:
//  r0 naive per-use loads, 512 thr                15.7 ms
//  r4 per-use + 4 accs + LN-fold, 512 thr          8.57 ms
//  r6 1024 thr + partial-z + packed LDS cache      7.95 ms
//  r7 row-major dwordx4 streaming, 1024 thr        7.09 ms
//  r8/r11/r12 wave-split @1024 thr (cap 64)       15-28 ms (spill)
//  r13 512 thr, RF(64 reg)+LDS(96KB) caches        6.84 ms  <- best
// LAWS: (1) VGPR cap = 65536/blockDim. Demand < cap is safe even across
//           barriers (r13: 64 cache regs, 1000 steps, zero scratch).
//       (2) Overlap must not replicate work (r9).
// r13 floor analysis: step 17.4 kcyc vs 8.5 kcyc port floor; gap = gate
// windows (port idle) + barrier drains + phase ramps at 2 waves/SIMD.
// This version = r13 memory scheme + r12 overlap structure (3 barriers):
//   A: all groups matvec0 (12 RF + 12 LDS + 8 streamed rows) -> zuA
//   B1; W2: tid<128 gates0  ||  groups 2,3: Wh1 x h1(t-1) -> zuB[2..3]
//           (240 KB of port work overlays the gates0 window)
//   B2; W3: groups 0,1: Wx1 x (gamma*h0)(t) -> zuB[0..1]
//   B3; wave-2 tail: gates1 (2 units/lane) + FC + softmax + store. NO B4;
//       waves 0,1,3..7 roll into A(t+1). Wave 2 chosen because it is NOT a
//       gates0 wave (load balance).
// Register budget: r13's ~110 + 4 tail-state scalars ~= 115 < 128.
// Kill signal: FETCH in GB => spilled => revert to r13 verbatim.
// ---------------------------------------------------------------------------

__device__ __forceinline__ float sigm(float x) {
    return 1.0f / (1.0f + __expf(-x));
}

// k = time_gate(t, tau, s); floor-mod semantics matching jnp.mod
__device__ __forceinline__ float tgate(float t, float tau, float s) {
    float r = fmodf(t - s, tau);
    if (r < 0.0f) r += tau;
    const float phi = r / tau;
    return (phi < 0.025f) ? 40.0f * phi
         : (phi < 0.05f)  ? 2.0f - 40.0f * phi
         : 0.001f * phi;
}

// 4-row FMA block from a weight POINTER (stride 128 float4 between rows).
#define ROW4(WP, I, HB) { \
    float4 w_; \
    w_ = (WP)[((I)+0)*128]; ac.x += (HB).x*w_.x; ac.y += (HB).x*w_.y; ac.z += (HB).x*w_.z; ac.w += (HB).x*w_.w; \
    w_ = (WP)[((I)+1)*128]; ac.x += (HB).y*w_.x; ac.y += (HB).y*w_.y; ac.z += (HB).y*w_.z; ac.w += (HB).y*w_.w; \
    w_ = (WP)[((I)+2)*128]; ac.x += (HB).z*w_.x; ac.y += (HB).z*w_.y; ac.z += (HB).z*w_.z; ac.w += (HB).z*w_.w; \
    w_ = (WP)[((I)+3)*128]; ac.x += (HB).w*w_.x; ac.y += (HB).w*w_.y; ac.z += (HB).w*w_.z; ac.w += (HB).w*w_.w; }

// 4-row FMA block from 4 REGISTER-cached weight float4s.
#define ROW4P(W0, W1, W2, W3, HB) { \
    ac.x += (HB).x*(W0).x; ac.y += (HB).x*(W0).y; ac.z += (HB).x*(W0).z; ac.w += (HB).x*(W0).w; \
    ac.x += (HB).y*(W1).x; ac.y += (HB).y*(W1).y; ac.z += (HB).y*(W1).z; ac.w += (HB).y*(W1).w; \
    ac.x += (HB).z*(W2).x; ac.y += (HB).z*(W2).y; ac.z += (HB).z*(W2).z; ac.w += (HB).z*(W2).w; \
    ac.x += (HB).w*(W3).x; ac.y += (HB).w*(W3).y; ac.z += (HB).w*(W3).z; ac.w += (HB).w*(W3).w; }

__global__ __launch_bounds__(512, 1) void plstm_fused(
    const float* __restrict__ inputs,  // [B,T,3]
    const float* __restrict__ times,   // [B,T]
    const float* __restrict__ Wx0,     // [3,512]
    const float* __restrict__ Wh0,     // [128,512]
    const float* __restrict__ b0,      // [512]
    const float* __restrict__ tau0,    // [128]
    const float* __restrict__ s0,      // [128]
    const float* __restrict__ Wx1,     // [128,512]
    const float* __restrict__ Wh1,     // [128,512]
    const float* __restrict__ b1,      // [512]
    const float* __restrict__ tau1,    // [128]
    const float* __restrict__ s1,      // [128]
    const float* __restrict__ gamma_,  // [128]
    const float* __restrict__ beta_,   // [128]
    const float* __restrict__ Wfc,     // [128,10]
    const float* __restrict__ bfc,     // [10]
    float* __restrict__ out)           // [B,T,10]
{
    const int tid = threadIdx.x;        // 0..511
    const int c4  = tid & 127;          // column quad (cols 4c4..4c4+3)
    const int g   = tid >> 7;           // rowgroup 0..3
    const int b   = blockIdx.x;

    __shared__ __align__(16) float wh0c[48 * G4];      // 96 KB: 12 rows/group
    __shared__ __align__(16) float zuA[4 * G4];        // 8 KB layer-0 partials
    __shared__ __align__(16) float zuB[4 * G4];        // 8 KB layer-1 partials
    __shared__ __align__(16) float h0s[U];             // h0 state
    __shared__ __align__(16) float ghu[2 * U];         // [0..127]=gamma*h0, [128..255]=h1
    __shared__ __align__(16) float b0s[G4], b1s[G4], Ps[G4], Qs[G4];
    __shared__ __align__(16) float wx0s[3 * G4];
    __shared__ __align__(16) float wfcs[U * 11];       // stride 11
    __shared__ float tau0s[U], s0s[U], tau1s[U], s1s[U];
    __shared__ float bfcs[NCls];
    __shared__ float red[4];                           // {sum0,sq0,sum1,sq1}
    __shared__ float gms[U], bts[U];

    // ---- prologue: stage everything ----
    if (tid < U) {
        gms[tid] = gamma_[tid]; bts[tid] = beta_[tid];
        tau0s[tid] = tau0[tid]; s0s[tid] = s0[tid];
        tau1s[tid] = tau1[tid]; s1s[tid] = s1[tid];
        h0s[tid] = 0.f; ghu[tid] = 0.f; ghu[U + tid] = 0.f;
    }
    {   // wh0c slot s (0..47) <-> Wh0 row 32*(s/12) + 12 + s%12
        float4* dst = reinterpret_cast<float4*>(wh0c);
        #pragma unroll
        for (int i = 0; i < 12; ++i) {
            const int idx  = i * 512 + tid;          // float4 index, 0..6143
            const int slot = idx >> 7;
            const int cq   = idx & 127;
            const int grp  = slot / 12;
            const int row  = 32 * grp + 12 + (slot - grp * 12);
            dst[slot * 128 + cq] =
                *reinterpret_cast<const float4*>(&Wh0[row * G4 + 4 * cq]);
        }
    }
    if (tid < G4) { b0s[tid] = b0[tid]; b1s[tid] = b1[tid]; }
    for (int i = tid; i < 3 * G4; i += 512) wx0s[i] = Wx0[i];
    for (int i = tid; i < U * NCls; i += 512) {
        const int u = i / NCls, c = i - u * NCls;
        wfcs[u * 11 + c] = Wfc[i];
    }
    if (tid < NCls) bfcs[tid] = bfc[tid];
    __syncthreads();

    // ---- LN fold constants: P[j]=sum beta[u]*Wx1[u][j], Q[j]=sum gamma[u]*Wx1[u][j]
    {
        float P = 0.f, Q = 0.f;
        #pragma unroll 8
        for (int u = 0; u < U; ++u) {
            const float w = Wx1[u * G4 + tid];
            Q += gms[u] * w;
            P += bts[u] * w;
        }
        Ps[tid] = P; Qs[tid] = Q;
    }

    // ---- register weight caches (loop-invariant; budgeted < 128) ----
    float4 wh0r[12];                        // Wh0 rows 32g..32g+11, my 4 cols
    #pragma unroll
    for (int i = 0; i < 12; ++i)
        wh0r[i] = *reinterpret_cast<const float4*>(&Wh0[(32 * g + i) * G4 + 4 * c4]);
    const float* __restrict__ Wc = (g < 2) ? Wx1 : Wh1;   // phase-C matrix
    const int rb = 64 * (g & 1);                          // phase-C row base
    float4 wcr[4];                          // first 4 C-rows, my 4 cols
    #pragma unroll
    for (int i = 0; i < 4; ++i)
        wcr[i] = *reinterpret_cast<const float4*>(&Wc[(rb + i) * G4 + 4 * c4]);

    // ---- recurrent state ----
    float c0r = 0.f, h0r = 0.f;                       // gates0 state (tid<128)
    float c1A = 0.f, h1A = 0.f, c1B = 0.f, h1B = 0.f; // gates1 state (wave 2)

    // ---- loop-invariant bases ----
    const float4* __restrict__ wlA =
        reinterpret_cast<const float4*>(wh0c) + (12 * g) * 128 + c4;   // LDS rows
    const float4* __restrict__ wsA =
        reinterpret_cast<const float4*>(Wh0) + (32 * g + 24) * 128 + c4;  // streamed A
    const float4* __restrict__ wsC =
        reinterpret_cast<const float4*>(Wc) + (rb + 4) * 128 + c4;     // streamed C
    const float* __restrict__ hvC = ghu + 64 * g;                      // C broadcast

    const float* __restrict__ xp = inputs + (size_t)b * TSTEPS * 3;
    const float* __restrict__ tp = times  + (size_t)b * TSTEPS;
    float*       __restrict__ op = out    + (size_t)b * TSTEPS * NCls;

    float xa0 = xp[0], xa1 = xp[1], xa2 = xp[2], tva = tp[0];

    __syncthreads();

    for (int t = 0; t < TSTEPS; ++t) {
        const float x0 = xa0, x1 = xa1, x2 = xa2, tv = tva;
        const int tn = (t + 1 < TSTEPS) ? t + 1 : t;
        xa0 = xp[tn*3+0]; xa1 = xp[tn*3+1]; xa2 = xp[tn*3+2]; tva = tp[tn];

        // ---- phase A: matvec0 (12 RF + 12 LDS + 8 streamed rows) -> zuA ----
        {
            float4 ac = make_float4(0.f, 0.f, 0.f, 0.f);
            {   // RF rows 32g..32g+11 (static indices only)
                const float4 hb0 = *reinterpret_cast<const float4*>(&h0s[32 * g + 0]);
                ROW4P(wh0r[0], wh0r[1], wh0r[2], wh0r[3], hb0);
                const float4 hb1 = *reinterpret_cast<const float4*>(&h0s[32 * g + 4]);
                ROW4P(wh0r[4], wh0r[5], wh0r[6], wh0r[7], hb1);
                const float4 hb2 = *reinterpret_cast<const float4*>(&h0s[32 * g + 8]);
                ROW4P(wh0r[8], wh0r[9], wh0r[10], wh0r[11], hb2);
            }
            #pragma unroll
            for (int i = 0; i < 12; i += 4) {   // LDS rows 32g+12..+23
                const float4 hb = *reinterpret_cast<const float4*>(&h0s[32 * g + 12 + i]);
                ROW4(wlA, i, hb);
            }
            #pragma unroll
            for (int i = 0; i < 8; i += 4) {    // streamed rows 32g+24..+31
                const float4 hb = *reinterpret_cast<const float4*>(&h0s[32 * g + 24 + i]);
                ROW4(wsA, i, hb);
            }
            *reinterpret_cast<float4*>(&zuA[g * G4 + 4 * c4]) = ac;
        }
        __syncthreads();                                   // ===== B1 =====

        // ---- W2: gates0 (tid<128) || groups 2,3: Wh1 x h1(t-1) -> zuB[2..3] ----
        if (tid < U) {
            const int u = tid;
            float z[4];
            #pragma unroll
            for (int q = 0; q < 4; ++q) {
                const int c = u + q * 128;
                float s = b0s[c] + x0 * wx0s[c] + x1 * wx0s[G4 + c] + x2 * wx0s[2 * G4 + c];
                s += (zuA[c] + zuA[G4 + c]) + (zuA[2 * G4 + c] + zuA[3 * G4 + c]);
                z[q] = s;
            }
            const float ig = sigm(z[0]), fg = sigm(z[1]);
            const float gg = tanhf(z[2]), og = sigm(z[3]);
            const float ch = fg * c0r + ig * gg;
            const float hh = og * tanhf(ch);
            const float k  = tgate(tv, tau0s[u], s0s[u]);
            const float hn = k * hh + (1.0f - k) * h0r;
            c0r = k * ch + (1.0f - k) * c0r;
            h0r = hn;
            h0s[u] = hn;
            ghu[u] = gms[u] * hn;
            float ssum = hn, qsum = hn * hn;               // one-pass variance
            #pragma unroll
            for (int off = 1; off < 64; off <<= 1) {
                ssum += __shfl_xor(ssum, off);
                qsum += __shfl_xor(qsum, off);
            }
            if ((tid & 63) == 0) {
                red[(tid >> 6) * 2]     = ssum;
                red[(tid >> 6) * 2 + 1] = qsum;
            }
        }
        if (g >= 2) {   // h1(t-1): written by wave 2 before it entered B1
            float4 ac = make_float4(0.f, 0.f, 0.f, 0.f);
            {   // RF rows rb..rb+3
                const float4 hb = *reinterpret_cast<const float4*>(&hvC[0]);
                ROW4P(wcr[0], wcr[1], wcr[2], wcr[3], hb);
            }
            #pragma unroll 5
            for (int i = 0; i < 60; i += 4) {   // streamed rows rb+4..rb+63
                const float4 hb = *reinterpret_cast<const float4*>(&hvC[4 + i]);
                ROW4(wsC, i, hb);
            }
            *reinterpret_cast<float4*>(&zuB[g * G4 + 4 * c4]) = ac;
        }
        __syncthreads();                                   // ===== B2 =====

        // ---- W3: groups 0,1: Wx1 x (gamma*h0)(t) -> zuB[0..1] ----
        if (g < 2) {
            float4 ac = make_float4(0.f, 0.f, 0.f, 0.f);
            {   // RF rows rb..rb+3
                const float4 hb = *reinterpret_cast<const float4*>(&hvC[0]);
                ROW4P(wcr[0], wcr[1], wcr[2], wcr[3], hb);
            }
            #pragma unroll 5
            for (int i = 0; i < 60; i += 4) {   // streamed rows rb+4..rb+63
                const float4 hb = *reinterpret_cast<const float4*>(&hvC[4 + i]);
                ROW4(wsC, i, hb);
            }
            *reinterpret_cast<float4*>(&zuB[g * G4 + 4 * c4]) = ac;
        }
        __syncthreads();                                   // ===== B3 =====

        // ---- wave-2 tail: gates1 (2 units/lane) + FC + softmax; NO barrier.
        //      Other waves roll into A(t+1). Hazards: zuB/red read here, next
        //      written after B1/B2(t+1) (wave 2 participates in those barriers,
        //      so its reads complete first). ghu[128..] written here before
        //      wave 2 enters B1(t+1); readers (groups 2,3 W2) read after
        //      B1(t+1). h0s/zuA untouched by the tail. ----
        if ((tid >> 6) == 2) {
            const int lane = tid & 63;
            const float mu    = (red[0] + red[2]) * (1.0f / 128.0f);
            const float msq   = (red[1] + red[3]) * (1.0f / 128.0f);
            const float rstd  = rsqrtf(msq - mu * mu + 1e-3f);
            const float murstd = mu * rstd;
            float hnv[2];
            #pragma unroll
            for (int e = 0; e < 2; ++e) {
                const int u = lane + e * 64;
                float z[4];
                #pragma unroll
                for (int q = 0; q < 4; ++q) {
                    const int c = u + q * 128;
                    const float sx = zuB[c] + zuB[G4 + c];              // Wx1 side
                    const float sh = zuB[2 * G4 + c] + zuB[3 * G4 + c]; // Wh1 side
                    // z1 = b1 + P + rstd*Swx - mu*rstd*Q + Swh (exact LN fold)
                    z[q] = b1s[c] + Ps[c] + rstd * sx - murstd * Qs[c] + sh;
                }
                const float ig = sigm(z[0]), fg = sigm(z[1]);
                const float gg = tanhf(z[2]), og = sigm(z[3]);
                const float cprev = e ? c1B : c1A;
                const float hprev = e ? h1B : h1A;
                const float ch = fg * cprev + ig * gg;
                const float hh = og * tanhf(ch);
                const float k  = tgate(tv, tau1s[u], s1s[u]);
                const float hn = k * hh + (1.0f - k) * hprev;
                if (e) { c1B = k * ch + (1.0f - k) * c1B; h1B = hn; }
                else   { c1A = k * ch + (1.0f - k) * c1A; h1A = hn; }
                ghu[U + u] = hn;
                hnv[e] = hn;
            }
            // FC + softmax entirely within wave 2
            float p[NCls];
            #pragma unroll
            for (int c = 0; c < NCls; ++c)
                p[c] = hnv[0] * wfcs[lane * 11 + c] + hnv[1] * wfcs[(lane + 64) * 11 + c];
            #pragma unroll
            for (int off = 1; off < 64; off <<= 1) {
                #pragma unroll
                for (int c = 0; c < NCls; ++c) p[c] += __shfl_xor(p[c], off);
            }
            float m = -1e30f;
            #pragma unroll
            for (int c = 0; c < NCls; ++c) { p[c] += bfcs[c]; m = fmaxf(m, p[c]); }
            float ssum = 0.0f;
            #pragma unroll
            for (int c = 0; c < NCls; ++c) { p[c] = __expf(p[c] - m); ssum += p[c]; }
            const float inv = 1.0f / ssum;
            float pv = p[0];               // static-index select (no scratch)
            #pragma unroll
            for (int c = 1; c < NCls; ++c) if (lane == c) pv = p[c];
            if (lane < NCls) op[t * NCls + lane] = pv * inv;
        }
    }
}

extern "C" void kernel_launch(void* const* d_in, const int* in_sizes, int n_in,
                              void* d_out, int out_size, void* d_ws, size_t ws_size,
                              hipStream_t stream) {
    const float* inputs = (const float*)d_in[0];
    const float* times  = (const float*)d_in[1];
    const float* Wx0    = (const float*)d_in[2];
    const float* Wh0    = (const float*)d_in[3];
    const float* b0     = (const float*)d_in[4];
    const float* tau0   = (const float*)d_in[5];
    const float* s0     = (const float*)d_in[6];
    const float* Wx1    = (const float*)d_in[7];
    const float* Wh1    = (const float*)d_in[8];
    const float* b1     = (const float*)d_in[9];
    const float* tau1   = (const float*)d_in[10];
    const float* s1     = (const float*)d_in[11];
    const float* gamma_ = (const float*)d_in[12];
    const float* beta_  = (const float*)d_in[13];
    const float* Wfc    = (const float*)d_in[14];
    const float* bfc    = (const float*)d_in[15];
    float* out = (float*)d_out;

    dim3 grid(BATCH);
    dim3 block(512);
    hipLaunchKernelGGL(plstm_fused, grid, block, 0, stream,
                       inputs, times, Wx0, Wh0, b0, tau0, s0,
                       Wx1, Wh1, b1, tau1, s1, gamma_, beta_, Wfc, bfc, out);
}

// Round 16
// 8182.475 us; speedup vs baseline: 1.3985x; 1.3985x over previous
//
#include <hip/hip_runtime.h>
#include <math.h>

// Problem constants (fixed by setup_inputs)
constexpr int U      = 128;   // UNITS
constexpr int G4     = 512;   // 4*U gate width
constexpr int NCls   = 10;    // classes
constexpr int TSTEPS = 1000;
constexpr int BATCH  = 256;

// ---------------------------------------------------------------------------
// Evidence ledger:
//  r0 naive per-use loads, 512 thr                15.7 ms
//  r4 per-use + 4 accs + LN-fold, 512 thr          8.57 ms
//  r7 row-major dwordx4 streaming, 1024 thr        7.09 ms
//  r13 512 thr, RF(64reg)+LDS(96KB) caches, 4bar   6.84 ms  <- best
//  r14 r13 + phase-C split across 2 windows       11.4 ms (half-concurrency)
//  r15 (this kernel) -- infra failure, no data; resubmitted unchanged.
// LAWS: (1) VGPR cap = 65536/blockDim; demand < cap is safe across barriers.
//       (2) Overlap must not replicate work (r9).
//       (3) Never reduce the number of waves concurrently streaming (r14) --
//           the ~35 B/cyc effective port rate needs all 8 waves issuing.
// MODEL: all healthy variants stream at ~35 B/cyc/CU (r4: 768KB/21.3kcyc,
//        r7: 672/18.5, r13: 544/17.4). Port-bound; bytes = the lever.
// This version = r13 + two deltas:
//  (a) LDS Wh0 cache 12 -> 14 rows/group (+16 KB LDS, -16 KB/step streamed):
//      per group: rows 0..11 RF | 12..25 LDS | 26..31 streamed.
//  (b) gates1+FC+softmax as a wave-2 tail after B3, NO B4; phase C stays
//      UNIFIED (all 8 waves in one window). Tail state = 4 scalars (fits:
//      r14 measured demand 108 < cap 128 with same state).
// Kill signal: FETCH in GB => spill => revert to r13 verbatim.
// ---------------------------------------------------------------------------

__device__ __forceinline__ float sigm(float x) {
    return 1.0f / (1.0f + __expf(-x));
}

// k = time_gate(t, tau, s); floor-mod semantics matching jnp.mod
__device__ __forceinline__ float tgate(float t, float tau, float s) {
    float r = fmodf(t - s, tau);
    if (r < 0.0f) r += tau;
    const float phi = r / tau;
    return (phi < 0.025f) ? 40.0f * phi
         : (phi < 0.05f)  ? 2.0f - 40.0f * phi
         : 0.001f * phi;
}

// 4-row FMA block from a weight POINTER (stride 128 float4 between rows).
#define ROW4(WP, I, HB) { \
    float4 w_; \
    w_ = (WP)[((I)+0)*128]; ac.x += (HB).x*w_.x; ac.y += (HB).x*w_.y; ac.z += (HB).x*w_.z; ac.w += (HB).x*w_.w; \
    w_ = (WP)[((I)+1)*128]; ac.x += (HB).y*w_.x; ac.y += (HB).y*w_.y; ac.z += (HB).y*w_.z; ac.w += (HB).y*w_.w; \
    w_ = (WP)[((I)+2)*128]; ac.x += (HB).z*w_.x; ac.y += (HB).z*w_.y; ac.z += (HB).z*w_.z; ac.w += (HB).z*w_.w; \
    w_ = (WP)[((I)+3)*128]; ac.x += (HB).w*w_.x; ac.y += (HB).w*w_.y; ac.z += (HB).w*w_.z; ac.w += (HB).w*w_.w; }

// 1-row FMA from a loaded weight float4 and scalar broadcast.
#define ROW1W(WQ, HS) { \
    ac.x += (HS)*(WQ).x; ac.y += (HS)*(WQ).y; ac.z += (HS)*(WQ).z; ac.w += (HS)*(WQ).w; }

// 4-row FMA block from 4 REGISTER-cached weight float4s.
#define ROW4P(W0, W1, W2, W3, HB) { \
    ac.x += (HB).x*(W0).x; ac.y += (HB).x*(W0).y; ac.z += (HB).x*(W0).z; ac.w += (HB).x*(W0).w; \
    ac.x += (HB).y*(W1).x; ac.y += (HB).y*(W1).y; ac.z += (HB).y*(W1).z; ac.w += (HB).y*(W1).w; \
    ac.x += (HB).z*(W2).x; ac.y += (HB).z*(W2).y; ac.z += (HB).z*(W2).z; ac.w += (HB).z*(W2).w; \
    ac.x += (HB).w*(W3).x; ac.y += (HB).w*(W3).y; ac.z += (HB).w*(W3).z; ac.w += (HB).w*(W3).w; }

__global__ __launch_bounds__(512, 1) void plstm_fused(
    const float* __restrict__ inputs,  // [B,T,3]
    const float* __restrict__ times,   // [B,T]
    const float* __restrict__ Wx0,     // [3,512]
    const float* __restrict__ Wh0,     // [128,512]
    const float* __restrict__ b0,      // [512]
    const float* __restrict__ tau0,    // [128]
    const float* __restrict__ s0,      // [128]
    const float* __restrict__ Wx1,     // [128,512]
    const float* __restrict__ Wh1,     // [128,512]
    const float* __restrict__ b1,      // [512]
    const float* __restrict__ tau1,    // [128]
    const float* __restrict__ s1,      // [128]
    const float* __restrict__ gamma_,  // [128]
    const float* __restrict__ beta_,   // [128]
    const float* __restrict__ Wfc,     // [128,10]
    const float* __restrict__ bfc,     // [10]
    float* __restrict__ out)           // [B,T,10]
{
    const int tid = threadIdx.x;        // 0..511
    const int c4  = tid & 127;          // column quad (cols 4c4..4c4+3)
    const int g   = tid >> 7;           // rowgroup 0..3
    const int b   = blockIdx.x;

    __shared__ __align__(16) float wh0c[56 * G4];      // 112 KB: 14 rows/group
    __shared__ __align__(16) float zuA[4 * G4];        // 8 KB layer-0 partials
    __shared__ __align__(16) float zuB[4 * G4];        // 8 KB layer-1 partials
    __shared__ __align__(16) float h0s[U];             // h0 state
    __shared__ __align__(16) float ghu[2 * U];         // [0..127]=gamma*h0, [128..255]=h1
    __shared__ __align__(16) float b0s[G4], b1s[G4], Ps[G4], Qs[G4];
    __shared__ __align__(16) float wx0s[3 * G4];
    __shared__ __align__(16) float wfcs[U * 11];       // stride 11
    __shared__ float tau0s[U], s0s[U], tau1s[U], s1s[U];
    __shared__ float bfcs[NCls];
    __shared__ float red[4];                           // {sum0,sq0,sum1,sq1}
    __shared__ float gms[U], bts[U];

    // ---- prologue: stage everything ----
    if (tid < U) {
        gms[tid] = gamma_[tid]; bts[tid] = beta_[tid];
        tau0s[tid] = tau0[tid]; s0s[tid] = s0[tid];
        tau1s[tid] = tau1[tid]; s1s[tid] = s1[tid];
        h0s[tid] = 0.f; ghu[tid] = 0.f; ghu[U + tid] = 0.f;
    }
    {   // wh0c slot s (0..55) <-> Wh0 row 32*(s/14) + 12 + s%14 (rows 12..25)
        float4* dst = reinterpret_cast<float4*>(wh0c);
        #pragma unroll
        for (int i = 0; i < 14; ++i) {
            const int idx  = i * 512 + tid;          // float4 index, 0..7167
            const int slot = idx >> 7;
            const int cq   = idx & 127;
            const int grp  = slot / 14;
            const int row  = 32 * grp + 12 + (slot - grp * 14);
            dst[slot * 128 + cq] =
                *reinterpret_cast<const float4*>(&Wh0[row * G4 + 4 * cq]);
        }
    }
    if (tid < G4) { b0s[tid] = b0[tid]; b1s[tid] = b1[tid]; }
    for (int i = tid; i < 3 * G4; i += 512) wx0s[i] = Wx0[i];
    for (int i = tid; i < U * NCls; i += 512) {
        const int u = i / NCls, c = i - u * NCls;
        wfcs[u * 11 + c] = Wfc[i];
    }
    if (tid < NCls) bfcs[tid] = bfc[tid];
    __syncthreads();

    // ---- LN fold constants: P[j]=sum beta[u]*Wx1[u][j], Q[j]=sum gamma[u]*Wx1[u][j]
    {
        float P = 0.f, Q = 0.f;
        #pragma unroll 8
        for (int u = 0; u < U; ++u) {
            const float w = Wx1[u * G4 + tid];
            Q += gms[u] * w;
            P += bts[u] * w;
        }
        Ps[tid] = P; Qs[tid] = Q;
    }

    // ---- register weight caches (loop-invariant; budgeted < 128) ----
    float4 wh0r[12];                        // Wh0 rows 32g..32g+11, my 4 cols
    #pragma unroll
    for (int i = 0; i < 12; ++i)
        wh0r[i] = *reinterpret_cast<const float4*>(&Wh0[(32 * g + i) * G4 + 4 * c4]);
    const float* __restrict__ Wc = (g < 2) ? Wx1 : Wh1;   // phase-C matrix
    const int rb = 64 * (g & 1);                          // phase-C row base
    float4 wcr[4];                          // first 4 C-rows, my 4 cols
    #pragma unroll
    for (int i = 0; i < 4; ++i)
        wcr[i] = *reinterpret_cast<const float4*>(&Wc[(rb + i) * G4 + 4 * c4]);

    // ---- recurrent state ----
    float c0r = 0.f, h0r = 0.f;                       // gates0 state (tid<128)
    float c1A = 0.f, h1A = 0.f, c1B = 0.f, h1B = 0.f; // gates1 state (wave 2)

    // ---- loop-invariant bases ----
    const float4* __restrict__ wlA =
        reinterpret_cast<const float4*>(wh0c) + (14 * g) * 128 + c4;   // LDS rows 12..25
    const float4* __restrict__ wsA =
        reinterpret_cast<const float4*>(Wh0) + (32 * g + 26) * 128 + c4;  // streamed 26..31
    const float4* __restrict__ wsC =
        reinterpret_cast<const float4*>(Wc) + (rb + 4) * 128 + c4;     // streamed C
    const float* __restrict__ hvC = ghu + 64 * g;                      // C broadcast

    const float* __restrict__ xp = inputs + (size_t)b * TSTEPS * 3;
    const float* __restrict__ tp = times  + (size_t)b * TSTEPS;
    float*       __restrict__ op = out    + (size_t)b * TSTEPS * NCls;

    float xa0 = xp[0], xa1 = xp[1], xa2 = xp[2], tva = tp[0];

    __syncthreads();

    for (int t = 0; t < TSTEPS; ++t) {
        const float x0 = xa0, x1 = xa1, x2 = xa2, tv = tva;
        const int tn = (t + 1 < TSTEPS) ? t + 1 : t;
        xa0 = xp[tn*3+0]; xa1 = xp[tn*3+1]; xa2 = xp[tn*3+2]; tva = tp[tn];

        // ---- phase A: matvec0 (12 RF + 14 LDS + 6 streamed rows) -> zuA ----
        {
            float4 ac = make_float4(0.f, 0.f, 0.f, 0.f);
            {   // RF rows 32g..32g+11 (static indices only)
                const float4 hb0 = *reinterpret_cast<const float4*>(&h0s[32 * g + 0]);
                ROW4P(wh0r[0], wh0r[1], wh0r[2], wh0r[3], hb0);
                const float4 hb1 = *reinterpret_cast<const float4*>(&h0s[32 * g + 4]);
                ROW4P(wh0r[4], wh0r[5], wh0r[6], wh0r[7], hb1);
                const float4 hb2 = *reinterpret_cast<const float4*>(&h0s[32 * g + 8]);
                ROW4P(wh0r[8], wh0r[9], wh0r[10], wh0r[11], hb2);
            }
            #pragma unroll
            for (int i = 0; i < 12; i += 4) {   // LDS rows 32g+12..+23 (slots 0..11)
                const float4 hb = *reinterpret_cast<const float4*>(&h0s[32 * g + 12 + i]);
                ROW4(wlA, i, hb);
            }
            {   // rows 24,25 from LDS (slots 12,13); rows 26,27 streamed
                const float4 hbX = *reinterpret_cast<const float4*>(&h0s[32 * g + 24]);
                float4 wq;
                wq = wlA[12 * 128]; ROW1W(wq, hbX.x);
                wq = wlA[13 * 128]; ROW1W(wq, hbX.y);
                wq = wsA[0 * 128];  ROW1W(wq, hbX.z);
                wq = wsA[1 * 128];  ROW1W(wq, hbX.w);
            }
            {   // streamed rows 28..31 (wsA offsets 2..5)
                const float4 hbY = *reinterpret_cast<const float4*>(&h0s[32 * g + 28]);
                ROW4(wsA, 2, hbY);
            }
            *reinterpret_cast<float4*>(&zuA[g * G4 + 4 * c4]) = ac;
        }
        __syncthreads();                                   // ===== B1 =====

        // ---- W2: gates0 + LN partials (tid < 128) ----
        if (tid < U) {
            const int u = tid;
            float z[4];
            #pragma unroll
            for (int q = 0; q < 4; ++q) {
                const int c = u + q * 128;
                float s = b0s[c] + x0 * wx0s[c] + x1 * wx0s[G4 + c] + x2 * wx0s[2 * G4 + c];
                s += (zuA[c] + zuA[G4 + c]) + (zuA[2 * G4 + c] + zuA[3 * G4 + c]);
                z[q] = s;
            }
            const float ig = sigm(z[0]), fg = sigm(z[1]);
            const float gg = tanhf(z[2]), og = sigm(z[3]);
            const float ch = fg * c0r + ig * gg;
            const float hh = og * tanhf(ch);
            const float k  = tgate(tv, tau0s[u], s0s[u]);
            const float hn = k * hh + (1.0f - k) * h0r;
            c0r = k * ch + (1.0f - k) * c0r;
            h0r = hn;
            h0s[u] = hn;
            ghu[u] = gms[u] * hn;
            float ssum = hn, qsum = hn * hn;               // one-pass variance
            #pragma unroll
            for (int off = 1; off < 64; off <<= 1) {
                ssum += __shfl_xor(ssum, off);
                qsum += __shfl_xor(qsum, off);
            }
            if ((tid & 63) == 0) {
                red[(tid >> 6) * 2]     = ssum;
                red[(tid >> 6) * 2 + 1] = qsum;
            }
        }
        __syncthreads();                                   // ===== B2 =====

        // ---- phase C (UNIFIED, all 8 waves): matvec1 (4 RF + 60 streamed) ----
        {
            float4 ac = make_float4(0.f, 0.f, 0.f, 0.f);
            {   // RF rows rb..rb+3
                const float4 hb = *reinterpret_cast<const float4*>(&hvC[0]);
                ROW4P(wcr[0], wcr[1], wcr[2], wcr[3], hb);
            }
            #pragma unroll 5
            for (int i = 0; i < 60; i += 4) {   // streamed rows rb+4..rb+63
                const float4 hb = *reinterpret_cast<const float4*>(&hvC[4 + i]);
                ROW4(wsC, i, hb);
            }
            *reinterpret_cast<float4*>(&zuB[g * G4 + 4 * c4]) = ac;
        }
        __syncthreads();                                   // ===== B3 =====

        // ---- wave-2 tail: gates1 (2 units/lane) + FC + softmax; NO B4.
        //      Other waves roll into A(t+1) (~3 kcyc of port work hides this).
        //      Hazards: zuB/red read here; next writers run after B2/B1(t+1),
        //      and wave 2 participates in those barriers after finishing, so
        //      its reads complete first. ghu[128..] written here before wave 2
        //      enters B1(t+1); readers (phase C groups 2,3) read after
        //      B2(t+1). Tail touches neither zuA nor h0s nor wh0c. ----
        if ((tid >> 6) == 2) {
            const int lane = tid & 63;
            const float mu    = (red[0] + red[2]) * (1.0f / 128.0f);
            const float msq   = (red[1] + red[3]) * (1.0f / 128.0f);
            const float rstd  = rsqrtf(msq - mu * mu + 1e-3f);
            const float murstd = mu * rstd;
            float hnv[2];
            #pragma unroll
            for (int e = 0; e < 2; ++e) {
                const int u = lane + e * 64;
                float z[4];
                #pragma unroll
                for (int q = 0; q < 4; ++q) {
                    const int c = u + q * 128;
                    const float sx = zuB[c] + zuB[G4 + c];              // Wx1 side
                    const float sh = zuB[2 * G4 + c] + zuB[3 * G4 + c]; // Wh1 side
                    // z1 = b1 + P + rstd*Swx - mu*rstd*Q + Swh (exact LN fold)
                    z[q] = b1s[c] + Ps[c] + rstd * sx - murstd * Qs[c] + sh;
                }
                const float ig = sigm(z[0]), fg = sigm(z[1]);
                const float gg = tanhf(z[2]), og = sigm(z[3]);
                const float cprev = e ? c1B : c1A;
                const float hprev = e ? h1B : h1A;
                const float ch = fg * cprev + ig * gg;
                const float hh = og * tanhf(ch);
                const float k  = tgate(tv, tau1s[u], s1s[u]);
                const float hn = k * hh + (1.0f - k) * hprev;
                if (e) { c1B = k * ch + (1.0f - k) * c1B; h1B = hn; }
                else   { c1A = k * ch + (1.0f - k) * c1A; h1A = hn; }
                ghu[U + u] = hn;
                hnv[e] = hn;
            }
            // FC + softmax entirely within wave 2
            float p[NCls];
            #pragma unroll
            for (int c = 0; c < NCls; ++c)
                p[c] = hnv[0] * wfcs[lane * 11 + c] + hnv[1] * wfcs[(lane + 64) * 11 + c];
            #pragma unroll
            for (int off = 1; off < 64; off <<= 1) {
                #pragma unroll
                for (int c = 0; c < NCls; ++c) p[c] += __shfl_xor(p[c], off);
            }
            float m = -1e30f;
            #pragma unroll
            for (int c = 0; c < NCls; ++c) { p[c] += bfcs[c]; m = fmaxf(m, p[c]); }
            float ssum = 0.0f;
            #pragma unroll
            for (int c = 0; c < NCls; ++c) { p[c] = __expf(p[c] - m); ssum += p[c]; }
            const float inv = 1.0f / ssum;
            float pv = p[0];               // static-index select (no scratch)
            #pragma unroll
            for (int c = 1; c < NCls; ++c) if (lane == c) pv = p[c];
            if (lane < NCls) op[t * NCls + lane] = pv * inv;
        }
    }
}

extern "C" void kernel_launch(void* const* d_in, const int* in_sizes, int n_in,
                              void* d_out, int out_size, void* d_ws, size_t ws_size,
                              hipStream_t stream) {
    const float* inputs = (const float*)d_in[0];
    const float* times  = (const float*)d_in[1];
    const float* Wx0    = (const float*)d_in[2];
    const float* Wh0    = (const float*)d_in[3];
    const float* b0     = (const float*)d_in[4];
    const float* tau0   = (const float*)d_in[5];
    const float* s0     = (const float*)d_in[6];
    const float* Wx1    = (const float*)d_in[7];
    const float* Wh1    = (const float*)d_in[8];
    const float* b1     = (const float*)d_in[9];
    const float* tau1   = (const float*)d_in[10];
    const float* s1     = (const float*)d_in[11];
    const float* gamma_ = (const float*)d_in[12];
    const float* beta_  = (const float*)d_in[13];
    const float* Wfc    = (const float*)d_in[14];
    const float* bfc    = (const float*)d_in[15];
    float* out = (float*)d_out;

    dim3 grid(BATCH);
    dim3 block(512);
    hipLaunchKernelGGL(plstm_fused, grid, block, 0, stream,
                       inputs, times, Wx0, Wh0, b0, tau0, s0,
                       Wx1, Wh1, b1, tau1, s1, gamma_, beta_, Wfc, bfc, out);
}

// Round 17
// 6886.792 us; speedup vs baseline: 1.6616x; 1.1881x over previous
//
#include <hip/hip_runtime.h>
#include <math.h>

// Problem constants (fixed by setup_inputs)
constexpr int U      = 128;   // UNITS
constexpr int G4     = 512;   // 4*U gate width
constexpr int NCls   = 10;    // classes
constexpr int TSTEPS = 1000;
constexpr int BATCH  = 256;

// ---------------------------------------------------------------------------
// Evidence ledger:
//  r0 naive per-use loads, 512 thr                15.7 ms
//  r4 per-use + 4 accs + LN-fold, 512 thr          8.57 ms
//  r7 row-major dwordx4 streaming, 1024 thr        7.09 ms
//  r13 512 thr, RF(64reg)+LDS(96KB) caches, 4bar   6.84 ms  <- best
//  r14 r13 + phase-C split across 2 windows       11.4 ms (half-concurrency)
//  r15/16 r13 + 14-row cache + wave-2 tail         8.18 ms (tail serialization)
// LAWS: (1) VGPR cap = 65536/blockDim; demand < cap is safe across barriers.
//       (2) Overlap must not replicate work (r9).
//       (3) Never reduce the number of waves concurrently streaming (r14).
//       (4) Don't concentrate serial work to save a barrier (r15/16): a
//           barrier costs ~100 cyc; a doubled per-wave serial chain ~1500.
// MODEL: healthy variants stream at ~32-35 B/cyc/CU from L2 (r4/r7/r13).
//        Port-bound; bytes are the only lever left.
// This version = r13 VERBATIM + ONLY the 14-row LDS cache (isolates r15's
// regression cause and trims 16 KB/step):
//   per group: Wh0 rows 0..11 RF | 12..25 LDS | 26..31 streamed.
//   Streamed: 528 KB/step. Barrier structure, gates, FC identical to r13.
// Kill signal: FETCH in GB => spill => r13 is final.
// ---------------------------------------------------------------------------

__device__ __forceinline__ float sigm(float x) {
    return 1.0f / (1.0f + __expf(-x));
}

// k = time_gate(t, tau, s); floor-mod semantics matching jnp.mod
__device__ __forceinline__ float tgate(float t, float tau, float s) {
    float r = fmodf(t - s, tau);
    if (r < 0.0f) r += tau;
    const float phi = r / tau;
    return (phi < 0.025f) ? 40.0f * phi
         : (phi < 0.05f)  ? 2.0f - 40.0f * phi
         : 0.001f * phi;
}

// 4-row FMA block from a weight POINTER (stride 128 float4 between rows).
#define ROW4(WP, I, HB) { \
    float4 w_; \
    w_ = (WP)[((I)+0)*128]; ac.x += (HB).x*w_.x; ac.y += (HB).x*w_.y; ac.z += (HB).x*w_.z; ac.w += (HB).x*w_.w; \
    w_ = (WP)[((I)+1)*128]; ac.x += (HB).y*w_.x; ac.y += (HB).y*w_.y; ac.z += (HB).y*w_.z; ac.w += (HB).y*w_.w; \
    w_ = (WP)[((I)+2)*128]; ac.x += (HB).z*w_.x; ac.y += (HB).z*w_.y; ac.z += (HB).z*w_.z; ac.w += (HB).z*w_.w; \
    w_ = (WP)[((I)+3)*128]; ac.x += (HB).w*w_.x; ac.y += (HB).w*w_.y; ac.z += (HB).w*w_.z; ac.w += (HB).w*w_.w; }

// 1-row FMA from a loaded weight float4 and scalar broadcast.
#define ROW1W(WQ, HS) { \
    ac.x += (HS)*(WQ).x; ac.y += (HS)*(WQ).y; ac.z += (HS)*(WQ).z; ac.w += (HS)*(WQ).w; }

// 4-row FMA block from 4 REGISTER-cached weight float4s.
#define ROW4P(W0, W1, W2, W3, HB) { \
    ac.x += (HB).x*(W0).x; ac.y += (HB).x*(W0).y; ac.z += (HB).x*(W0).z; ac.w += (HB).x*(W0).w; \
    ac.x += (HB).y*(W1).x; ac.y += (HB).y*(W1).y; ac.z += (HB).y*(W1).z; ac.w += (HB).y*(W1).w; \
    ac.x += (HB).z*(W2).x; ac.y += (HB).z*(W2).y; ac.z += (HB).z*(W2).z; ac.w += (HB).z*(W2).w; \
    ac.x += (HB).w*(W3).x; ac.y += (HB).w*(W3).y; ac.z += (HB).w*(W3).z; ac.w += (HB).w*(W3).w; }

__global__ __launch_bounds__(512, 1) void plstm_fused(
    const float* __restrict__ inputs,  // [B,T,3]
    const float* __restrict__ times,   // [B,T]
    const float* __restrict__ Wx0,     // [3,512]
    const float* __restrict__ Wh0,     // [128,512]
    const float* __restrict__ b0,      // [512]
    const float* __restrict__ tau0,    // [128]
    const float* __restrict__ s0,      // [128]
    const float* __restrict__ Wx1,     // [128,512]
    const float* __restrict__ Wh1,     // [128,512]
    const float* __restrict__ b1,      // [512]
    const float* __restrict__ tau1,    // [128]
    const float* __restrict__ s1,      // [128]
    const float* __restrict__ gamma_,  // [128]
    const float* __restrict__ beta_,   // [128]
    const float* __restrict__ Wfc,     // [128,10]
    const float* __restrict__ bfc,     // [10]
    float* __restrict__ out)           // [B,T,10]
{
    const int tid = threadIdx.x;        // 0..511
    const int c4  = tid & 127;          // column quad (cols 4c4..4c4+3)
    const int g   = tid >> 7;           // rowgroup 0..3
    const int b   = blockIdx.x;

    __shared__ __align__(16) float wh0c[56 * G4];      // 112 KB: 14 rows/group
    __shared__ __align__(16) float zuA[4 * G4];        // 8 KB layer-0 partials
    __shared__ __align__(16) float zuB[4 * G4];        // 8 KB layer-1 partials
    __shared__ __align__(16) float h0s[U];             // h0 state
    __shared__ __align__(16) float ghu[2 * U];         // [0..127]=gamma*h0, [128..255]=h1
    __shared__ __align__(16) float b0s[G4], b1s[G4], Ps[G4], Qs[G4];
    __shared__ __align__(16) float wx0s[3 * G4];
    __shared__ __align__(16) float wfcs[U * 11];       // stride 11
    __shared__ float tau0s[U], s0s[U], tau1s[U], s1s[U];
    __shared__ float bfcs[NCls];
    __shared__ float red[4];                           // {sum0,sq0,sum1,sq1}
    __shared__ float gms[U], bts[U];

    // ---- prologue: stage everything ----
    if (tid < U) {
        gms[tid] = gamma_[tid]; bts[tid] = beta_[tid];
        tau0s[tid] = tau0[tid]; s0s[tid] = s0[tid];
        tau1s[tid] = tau1[tid]; s1s[tid] = s1[tid];
        h0s[tid] = 0.f; ghu[tid] = 0.f; ghu[U + tid] = 0.f;
    }
    {   // wh0c slot s (0..55) <-> Wh0 row 32*(s/14) + 12 + s%14 (rows 12..25)
        float4* dst = reinterpret_cast<float4*>(wh0c);
        #pragma unroll
        for (int i = 0; i < 14; ++i) {
            const int idx  = i * 512 + tid;          // float4 index, 0..7167
            const int slot = idx >> 7;
            const int cq   = idx & 127;
            const int grp  = slot / 14;
            const int row  = 32 * grp + 12 + (slot - grp * 14);
            dst[slot * 128 + cq] =
                *reinterpret_cast<const float4*>(&Wh0[row * G4 + 4 * cq]);
        }
    }
    if (tid < G4) { b0s[tid] = b0[tid]; b1s[tid] = b1[tid]; }
    for (int i = tid; i < 3 * G4; i += 512) wx0s[i] = Wx0[i];
    for (int i = tid; i < U * NCls; i += 512) {
        const int u = i / NCls, c = i - u * NCls;
        wfcs[u * 11 + c] = Wfc[i];
    }
    if (tid < NCls) bfcs[tid] = bfc[tid];
    __syncthreads();

    // ---- LN fold constants: P[j]=sum beta[u]*Wx1[u][j], Q[j]=sum gamma[u]*Wx1[u][j]
    {
        float P = 0.f, Q = 0.f;
        #pragma unroll 8
        for (int u = 0; u < U; ++u) {
            const float w = Wx1[u * G4 + tid];
            Q += gms[u] * w;
            P += bts[u] * w;
        }
        Ps[tid] = P; Qs[tid] = Q;
    }

    // ---- register weight caches (loop-invariant; budgeted < 128) ----
    float4 wh0r[12];                        // Wh0 rows 32g..32g+11, my 4 cols
    #pragma unroll
    for (int i = 0; i < 12; ++i)
        wh0r[i] = *reinterpret_cast<const float4*>(&Wh0[(32 * g + i) * G4 + 4 * c4]);
    const float* __restrict__ Wc = (g < 2) ? Wx1 : Wh1;   // phase-C matrix
    const int rb = 64 * (g & 1);                          // phase-C row base
    float4 wcr[4];                          // first 4 C-rows, my 4 cols
    #pragma unroll
    for (int i = 0; i < 4; ++i)
        wcr[i] = *reinterpret_cast<const float4*>(&Wc[(rb + i) * G4 + 4 * c4]);

    // ---- recurrent state (tid<128 only meaningful) ----
    float c0r = 0.f, h0r = 0.f, c1r = 0.f, h1r = 0.f;

    // ---- loop-invariant bases ----
    const float4* __restrict__ wlA =
        reinterpret_cast<const float4*>(wh0c) + (14 * g) * 128 + c4;   // LDS rows 12..25
    const float4* __restrict__ wsA =
        reinterpret_cast<const float4*>(Wh0) + (32 * g + 26) * 128 + c4;  // streamed 26..31
    const float4* __restrict__ wsC =
        reinterpret_cast<const float4*>(Wc) + (rb + 4) * 128 + c4;     // streamed C
    const float* __restrict__ hvC = ghu + 64 * g;                      // C broadcast

    const float* __restrict__ xp = inputs + (size_t)b * TSTEPS * 3;
    const float* __restrict__ tp = times  + (size_t)b * TSTEPS;
    float*       __restrict__ op = out    + (size_t)b * TSTEPS * NCls;

    float xa0 = xp[0], xa1 = xp[1], xa2 = xp[2], tva = tp[0];

    __syncthreads();

    for (int t = 0; t < TSTEPS; ++t) {
        const float x0 = xa0, x1 = xa1, x2 = xa2, tv = tva;
        const int tn = (t + 1 < TSTEPS) ? t + 1 : t;
        xa0 = xp[tn*3+0]; xa1 = xp[tn*3+1]; xa2 = xp[tn*3+2]; tva = tp[tn];

        // ---- phase A: matvec0 (12 RF + 14 LDS + 6 streamed rows) -> zuA ----
        {
            float4 ac = make_float4(0.f, 0.f, 0.f, 0.f);
            {   // RF rows 32g..32g+11 (static indices only)
                const float4 hb0 = *reinterpret_cast<const float4*>(&h0s[32 * g + 0]);
                ROW4P(wh0r[0], wh0r[1], wh0r[2], wh0r[3], hb0);
                const float4 hb1 = *reinterpret_cast<const float4*>(&h0s[32 * g + 4]);
                ROW4P(wh0r[4], wh0r[5], wh0r[6], wh0r[7], hb1);
                const float4 hb2 = *reinterpret_cast<const float4*>(&h0s[32 * g + 8]);
                ROW4P(wh0r[8], wh0r[9], wh0r[10], wh0r[11], hb2);
            }
            #pragma unroll
            for (int i = 0; i < 12; i += 4) {   // LDS rows 32g+12..+23 (slots 0..11)
                const float4 hb = *reinterpret_cast<const float4*>(&h0s[32 * g + 12 + i]);
                ROW4(wlA, i, hb);
            }
            {   // rows 24,25 from LDS (slots 12,13); rows 26,27 streamed
                const float4 hbX = *reinterpret_cast<const float4*>(&h0s[32 * g + 24]);
                float4 wq;
                wq = wlA[12 * 128]; ROW1W(wq, hbX.x);
                wq = wlA[13 * 128]; ROW1W(wq, hbX.y);
                wq = wsA[0 * 128];  ROW1W(wq, hbX.z);
                wq = wsA[1 * 128];  ROW1W(wq, hbX.w);
            }
            {   // streamed rows 28..31 (wsA offsets 2..5)
                const float4 hbY = *reinterpret_cast<const float4*>(&h0s[32 * g + 28]);
                ROW4(wsA, 2, hbY);
            }
            *reinterpret_cast<float4*>(&zuA[g * G4 + 4 * c4]) = ac;
        }
        __syncthreads();                                   // ===== B1 =====

        // ---- gates0 + LN partials (tid < 128) ----
        if (tid < U) {
            const int u = tid;
            float z[4];
            #pragma unroll
            for (int q = 0; q < 4; ++q) {
                const int c = u + q * 128;
                float s = b0s[c] + x0 * wx0s[c] + x1 * wx0s[G4 + c] + x2 * wx0s[2 * G4 + c];
                s += (zuA[c] + zuA[G4 + c]) + (zuA[2 * G4 + c] + zuA[3 * G4 + c]);
                z[q] = s;
            }
            const float ig = sigm(z[0]), fg = sigm(z[1]);
            const float gg = tanhf(z[2]), og = sigm(z[3]);
            const float ch = fg * c0r + ig * gg;
            const float hh = og * tanhf(ch);
            const float k  = tgate(tv, tau0s[u], s0s[u]);
            const float hn = k * hh + (1.0f - k) * h0r;
            c0r = k * ch + (1.0f - k) * c0r;
            h0r = hn;
            h0s[u] = hn;
            ghu[u] = gms[u] * hn;
            float ssum = hn, qsum = hn * hn;               // one-pass variance
            #pragma unroll
            for (int off = 1; off < 64; off <<= 1) {
                ssum += __shfl_xor(ssum, off);
                qsum += __shfl_xor(qsum, off);
            }
            if ((tid & 63) == 0) {
                red[(tid >> 6) * 2]     = ssum;
                red[(tid >> 6) * 2 + 1] = qsum;
            }
        }
        __syncthreads();                                   // ===== B2 =====

        // ---- phase C (UNIFIED, all 8 waves): matvec1 (4 RF + 60 streamed) ----
        {
            float4 ac = make_float4(0.f, 0.f, 0.f, 0.f);
            {   // RF rows rb..rb+3
                const float4 hb = *reinterpret_cast<const float4*>(&hvC[0]);
                ROW4P(wcr[0], wcr[1], wcr[2], wcr[3], hb);
            }
            #pragma unroll 5
            for (int i = 0; i < 60; i += 4) {   // streamed rows rb+4..rb+63
                const float4 hb = *reinterpret_cast<const float4*>(&hvC[4 + i]);
                ROW4(wsC, i, hb);
            }
            *reinterpret_cast<float4*>(&zuB[g * G4 + 4 * c4]) = ac;
        }
        __syncthreads();                                   // ===== B3 =====

        // ---- gates1 with LN fold (tid < 128) ----
        if (tid < U) {
            const float mu    = (red[0] + red[2]) * (1.0f / 128.0f);
            const float msq   = (red[1] + red[3]) * (1.0f / 128.0f);
            const float rstd  = rsqrtf(msq - mu * mu + 1e-3f);
            const float murstd = mu * rstd;
            const int u = tid;
            float z[4];
            #pragma unroll
            for (int q = 0; q < 4; ++q) {
                const int c = u + q * 128;
                const float sx = zuB[c] + zuB[G4 + c];              // Wx1 side
                const float sh = zuB[2 * G4 + c] + zuB[3 * G4 + c]; // Wh1 side
                // z1 = b1 + P + rstd*Swx - mu*rstd*Q + Swh (exact LN fold)
                z[q] = b1s[c] + Ps[c] + rstd * sx - murstd * Qs[c] + sh;
            }
            const float ig = sigm(z[0]), fg = sigm(z[1]);
            const float gg = tanhf(z[2]), og = sigm(z[3]);
            const float ch = fg * c1r + ig * gg;
            const float hh = og * tanhf(ch);
            const float k  = tgate(tv, tau1s[u], s1s[u]);
            const float hn = k * hh + (1.0f - k) * h1r;
            c1r = k * ch + (1.0f - k) * c1r;
            h1r = hn;
            ghu[U + u] = hn;                               // h1 state
        }
        __syncthreads();                                   // ===== B4 =====

        // ---- FC + softmax (wave 0); other waves roll into A(t+1) ----
        if (tid < 64) {
            const float a  = ghu[U + tid];
            const float bv = ghu[U + tid + 64];
            float p[NCls];
            #pragma unroll
            for (int c = 0; c < NCls; ++c)
                p[c] = a * wfcs[tid * 11 + c] + bv * wfcs[(tid + 64) * 11 + c];
            #pragma unroll
            for (int off = 1; off < 64; off <<= 1) {
                #pragma unroll
                for (int c = 0; c < NCls; ++c) p[c] += __shfl_xor(p[c], off);
            }
            float m = -1e30f;
            #pragma unroll
            for (int c = 0; c < NCls; ++c) { p[c] += bfcs[c]; m = fmaxf(m, p[c]); }
            float ssum = 0.0f;
            #pragma unroll
            for (int c = 0; c < NCls; ++c) { p[c] = __expf(p[c] - m); ssum += p[c]; }
            const float inv = 1.0f / ssum;
            float pv = p[0];               // static-index select (no scratch)
            #pragma unroll
            for (int c = 1; c < NCls; ++c) if (tid == c) pv = p[c];
            if (tid < NCls) op[t * NCls + tid] = pv * inv;
        }
        // No trailing barrier: A(t+1) writes zuA (last read in gates0 before
        // B2) and reads h0s (written before B2); FC reads ghu[128..]/wfcs,
        // next written in gates1(t+1) behind B1..B3. All hazards fenced.
    }
}

extern "C" void kernel_launch(void* const* d_in, const int* in_sizes, int n_in,
                              void* d_out, int out_size, void* d_ws, size_t ws_size,
                              hipStream_t stream) {
    const float* inputs = (const float*)d_in[0];
    const float* times  = (const float*)d_in[1];
    const float* Wx0    = (const float*)d_in[2];
    const float* Wh0    = (const float*)d_in[3];
    const float* b0     = (const float*)d_in[4];
    const float* tau0   = (const float*)d_in[5];
    const float* s0     = (const float*)d_in[6];
    const float* Wx1    = (const float*)d_in[7];
    const float* Wh1    = (const float*)d_in[8];
    const float* b1     = (const float*)d_in[9];
    const float* tau1   = (const float*)d_in[10];
    const float* s1     = (const float*)d_in[11];
    const float* gamma_ = (const float*)d_in[12];
    const float* beta_  = (const float*)d_in[13];
    const float* Wfc    = (const float*)d_in[14];
    const float* bfc    = (const float*)d_in[15];
    float* out = (float*)d_out;

    dim3 grid(BATCH);
    dim3 block(512);
    hipLaunchKernelGGL(plstm_fused, grid, block, 0, stream,
                       inputs, times, Wx0, Wh0, b0, tau0, s0,
                       Wx1, Wh1, b1, tau1, s1, gamma_, beta_, Wfc, bfc, out);
}